// Round 1
// baseline (1945.900 us; speedup 1.0000x reference)
//
#include <hip/hip_runtime.h>

// TT-linear: y[b, n1*256+n2*16+n3] = sum_{m1,m2,m3,r1,r2}
//   x[b, m1*256+m2*16+m3] * C0[m1,n1,r1] * C1[r1,m2,n2,r2] * C2[r2,m3,n3] + bias
//
// Fused per-token kernel, slab-streamed over m3:
//   T1[m2,n1,r1] = sum_m1 X[m1,m2,m3] * C0[m1,n1,r1]          (per m3 slab)
//   T2[n1,n2,r2] = sum_{m2,r1} T1[m2,n1,r1] * C1[r1,m2,n2,r2] (per m3 slab)
//   Y[n1,n2,n3] += sum_r2 T2[n1,n2,r2] * C2[r2,m3,n3]         (accum over m3)
// One workgroup (256 threads) per token. Intermediates live in LDS only.

__global__ __launch_bounds__(256) void tt_fp32_kernel(
    const float* __restrict__ x, const float* __restrict__ c0,
    const float* __restrict__ c1, const float* __restrict__ c2,
    const float* __restrict__ bias, float* __restrict__ out)
{
    __shared__ float sX[4096];   // X[m1][m2][m3] : m1*256 + m2*16 + m3
    __shared__ float sC0[2048];  // C0[m1][n1][r1]: m1*128 + n1*8 + r1
    __shared__ float sC2[2048];  // C2[r2][m3][n3]: (r2*16+m3)*16 + n3
    __shared__ float sT1[2048];  // T1[m2][n1][r1]: m2*128 + n1*8 + r1
    __shared__ float sT2[2048];  // T2[n1][n2][r2]: (n1*16+n2)*8 + r2

    const int b   = blockIdx.x;
    const int tid = threadIdx.x;

    // ---- stage X (16 KB) + small cores (8 KB each), coalesced float4 ----
    {
        const float4* xs = (const float4*)(x + (size_t)b * 4096);
        float4* dX = (float4*)sX;
        #pragma unroll
        for (int i = 0; i < 4; ++i) dX[tid + 256 * i] = xs[tid + 256 * i];

        const float4* c0s = (const float4*)c0;
        float4* d0 = (float4*)sC0;
        d0[tid] = c0s[tid];
        d0[tid + 256] = c0s[tid + 256];

        const float4* c2s = (const float4*)c2;
        float4* d2 = (float4*)sC2;
        d2[tid] = c2s[tid];
        d2[tid + 256] = c2s[tid + 256];
    }
    __syncthreads();

    const int n1 = tid >> 4;   // [0,16)
    const int n2 = tid & 15;   // [0,16)

    float accY[16];
    #pragma unroll
    for (int i = 0; i < 16; ++i) accY[i] = 0.f;

    for (int m3 = 0; m3 < 16; ++m3) {
        // ---- Step 1: T1[m2][n1p][r1], thread = (m2 = tid>>4, n1p = tid&15) ----
        {
            const int m2 = tid >> 4, n1p = tid & 15;
            float a[8] = {0.f, 0.f, 0.f, 0.f, 0.f, 0.f, 0.f, 0.f};
            #pragma unroll
            for (int m1 = 0; m1 < 16; ++m1) {
                const float xv = sX[m1 * 256 + m2 * 16 + m3];
                const float* cp = &sC0[m1 * 128 + n1p * 8];
                #pragma unroll
                for (int r1 = 0; r1 < 8; ++r1) a[r1] += xv * cp[r1];
            }
            float* tp = &sT1[m2 * 128 + n1p * 8];
            #pragma unroll
            for (int r1 = 0; r1 < 8; ++r1) tp[r1] = a[r1];
        }
        __syncthreads();

        // ---- Step 2 (dominant): T2[n1][n2][r2] = sum_{m2,r1} T1*C1 ----
        // C1 read from global (L1/L2-hot; per (m2,r1) the wave touches one
        // contiguous 512 B line: addr = (((r1*16+m2)*16+n2)*8)*4B, n2 fastest).
        {
            float a[8] = {0.f, 0.f, 0.f, 0.f, 0.f, 0.f, 0.f, 0.f};
            #pragma unroll 4
            for (int m2 = 0; m2 < 16; ++m2) {
                const float* t1p = &sT1[m2 * 128 + n1 * 8];
                #pragma unroll
                for (int r1 = 0; r1 < 8; ++r1) {
                    const float t = t1p[r1];
                    const float4* cp = (const float4*)&c1[((r1 * 16 + m2) * 16 + n2) * 8];
                    const float4 cA = cp[0];
                    const float4 cB = cp[1];
                    a[0] += t * cA.x; a[1] += t * cA.y;
                    a[2] += t * cA.z; a[3] += t * cA.w;
                    a[4] += t * cB.x; a[5] += t * cB.y;
                    a[6] += t * cB.z; a[7] += t * cB.w;
                }
            }
            float* tp = &sT2[(n1 * 16 + n2) * 8];
            #pragma unroll
            for (int r2 = 0; r2 < 8; ++r2) tp[r2] = a[r2];
        }
        __syncthreads();

        // ---- Step 3: accY[n3] += sum_r2 T2[n1][n2][r2] * C2[r2][m3][n3] ----
        // (no barrier needed after: next iter's step-1 sync orders T2 reuse)
        {
            const float* t2p = &sT2[(n1 * 16 + n2) * 8];
            #pragma unroll
            for (int r2 = 0; r2 < 8; ++r2) {
                const float t = t2p[r2];
                const float* cp = &sC2[(r2 * 16 + m3) * 16];  // uniform -> LDS broadcast
                #pragma unroll
                for (int n3 = 0; n3 < 16; ++n3) accY[n3] += t * cp[n3];
            }
        }
    }

    // ---- epilogue: out[b, n1*256+n2*16+n3] = accY + bias ----
    {
        const int o = n1 * 256 + n2 * 16;
        const float4* bp = (const float4*)(bias + o);
        float4* op = (float4*)(out + (size_t)b * 4096 + o);
        #pragma unroll
        for (int i = 0; i < 4; ++i) {
            float4 v = bp[i];
            v.x += accY[i * 4 + 0];
            v.y += accY[i * 4 + 1];
            v.z += accY[i * 4 + 2];
            v.w += accY[i * 4 + 3];
            op[i] = v;
        }
    }
}

extern "C" void kernel_launch(void* const* d_in, const int* in_sizes, int n_in,
                              void* d_out, int out_size, void* d_ws, size_t ws_size,
                              hipStream_t stream) {
    const float* x    = (const float*)d_in[0];
    const float* c0   = (const float*)d_in[1];  // (1,16,16,8)
    const float* c1   = (const float*)d_in[2];  // (8,16,16,8)
    const float* c2   = (const float*)d_in[3];  // (8,16,16,1)
    const float* bias = (const float*)d_in[4];  // (4096,)
    float* out = (float*)d_out;

    tt_fp32_kernel<<<4096, 256, 0, stream>>>(x, c0, c1, c2, bias, out);
}

// Round 2
// 352.035 us; speedup vs baseline: 5.5276x; 5.5276x over previous
//
#include <hip/hip_runtime.h>

// TT-linear via 3 chained GEMMs per token, one 512-thread WG (8 waves) per token.
//   G1 (fp32 VALU): T1[m3l,n1][m2,r1] = sum_m1 X[m1,m2,m3] * C0[m1,n1,r1]   (per slab of 4 m3)
//   G2 (bf16 MFMA): T2[(m3l,n1)][(n2,r2)] = T1 @ C1  (M=64,N=128,K=128)
//   G3 (bf16 MFMA): Y[(n1,n2)][n3] += T2' @ C2       (K=32/slab, acc across slabs)
// C1/C2 MFMA B-fragments live in registers, loaded once per WG (token-invariant).
// LDS tiles padded (stride 136 / 40 elems) so every ds_*_b128 spreads across all
// 8 four-bank groups -> conflict-free. Static LDS = 61 KB -> 2 WG/CU.

typedef __attribute__((ext_vector_type(8))) short bf16x8;
typedef __attribute__((ext_vector_type(4))) float f32x4;

__device__ __forceinline__ unsigned short f2bf(float f) {
    unsigned u = __builtin_bit_cast(unsigned, f);
    u += 0x7FFFu + ((u >> 16) & 1u);   // round-to-nearest-even
    return (unsigned short)(u >> 16);
}

union BF8 { bf16x8 v; unsigned short s[8]; uint4 u4; };

__global__ __launch_bounds__(512, 2) void tt_mfma_kernel(
    const float* __restrict__ x, const float* __restrict__ c0,
    const float* __restrict__ c1, const float* __restrict__ c2,
    const float* __restrict__ bias, float* __restrict__ out)
{
    __shared__ float sX[4096];                 // X[m1][m2][m3] (global layout), 16 KB
    __shared__ float sC0[2048];                // C0[m1][n1][r1], 8 KB
    __shared__ unsigned short sA2[64 * 136];   // T1 bf16, row m=(m3l*16+n1), k=(m2*8+r1), pad->136
    __shared__ unsigned short sT2[256 * 40];   // T2 bf16, row m'=(n1*16+n2), k=(m3l*8+r2), pad->40

    const int b    = blockIdx.x;
    const int tid  = threadIdx.x;
    const int w    = tid >> 6;       // wave 0..7
    const int lane = tid & 63;
    const int q    = lane >> 4;      // quad 0..3
    const int col  = lane & 15;

    // ---- stage X (full token) + C0, perfectly coalesced float4 ----
    {
        const float4* xg = (const float4*)(x + (size_t)b * 4096);
        float4* dX = (float4*)sX;
        dX[tid]       = xg[tid];
        dX[tid + 512] = xg[tid + 512];
        ((float4*)sC0)[tid] = ((const float4*)c0)[tid];
    }

    // ---- preload G2 B-fragments (C1) into registers: wave -> nt = ntbase..+3 ----
    // B[k=(m2*8+r1)][n=(n2*8+r2)]: lane holds k = k4*32 + q*8 + j  (m2=k4*4+q, r1=j)
    BF8 bF[4][4];
    const int ntbase = (w >> 2) * 4;
    #pragma unroll
    for (int i = 0; i < 4; ++i) {
        const int n  = (ntbase + i) * 16 + col;   // n = n2*8 + r2
        const int n2 = n >> 3, r2 = n & 7;
        #pragma unroll
        for (int k4 = 0; k4 < 4; ++k4) {
            const int m2 = k4 * 4 + q;
            #pragma unroll
            for (int j = 0; j < 8; ++j)           // r1 = j
                bF[i][k4].s[j] = f2bf(c1[((j * 16 + m2) * 16 + n2) * 8 + r2]);
        }
    }
    // ---- preload G3 B-fragments (C2): B[k=(m3*8+r2)][n3], slab s: m3=s*4+q, r2=j ----
    BF8 b3[4];
    #pragma unroll
    for (int s = 0; s < 4; ++s)
        #pragma unroll
        for (int j = 0; j < 8; ++j)
            b3[s].s[j] = f2bf(c2[(j * 16 + s * 4 + q) * 16 + col]);

    f32x4 acc3[2] = {{0.f,0.f,0.f,0.f},{0.f,0.f,0.f,0.f}};

    // step-1 thread map: tid = m2s*32 + n1p*2 + h
    const int m2s = tid >> 5;
    const int n1p = (tid >> 1) & 15;
    const int h   = tid & 1;

    for (int s = 0; s < 4; ++s) {
        __syncthreads();   // (iter 0: orders staging; later: sA2/sT2 reuse)

        // ---- G1: fp32 VALU, T1 slab -> sA2 (bf16, A-layout, b128 write) ----
        #pragma unroll
        for (int mm = 0; mm < 2; ++mm) {
            const int m3l = 2 * h + mm;
            const int m3  = s * 4 + m3l;
            float a[8] = {0,0,0,0,0,0,0,0};
            #pragma unroll
            for (int m1 = 0; m1 < 16; ++m1) {
                const float xv = sX[m1 * 256 + m2s * 16 + m3];
                const float* cp = &sC0[m1 * 128 + n1p * 8];
                #pragma unroll
                for (int r1 = 0; r1 < 8; ++r1) a[r1] += xv * cp[r1];
            }
            BF8 pk;
            #pragma unroll
            for (int r1 = 0; r1 < 8; ++r1) pk.s[r1] = f2bf(a[r1]);
            *(uint4*)&sA2[(m3l * 16 + n1p) * 136 + m2s * 8] = pk.u4;
        }
        __syncthreads();

        // ---- G2 MFMA: wave w does mt = w&3 (= m3l), nt = ntbase..+3 ----
        {
            const int mt = w & 3;
            bf16x8 aF[4];
            #pragma unroll
            for (int k4 = 0; k4 < 4; ++k4)
                aF[k4] = *(const bf16x8*)&sA2[(mt * 16 + col) * 136 + k4 * 32 + q * 8];
            #pragma unroll
            for (int i = 0; i < 4; ++i) {
                f32x4 acc = {0.f,0.f,0.f,0.f};
                #pragma unroll
                for (int k4 = 0; k4 < 4; ++k4)
                    acc = __builtin_amdgcn_mfma_f32_16x16x32_bf16(aF[k4], bF[i][k4].v, acc, 0, 0, 0);
                const int nt = ntbase + i;
                const int n2 = nt * 2 + (col >> 3), r2 = col & 7;
                #pragma unroll
                for (int r = 0; r < 4; ++r) {
                    const int n1 = q * 4 + r;                  // D row within tile
                    sT2[(n1 * 16 + n2) * 40 + mt * 8 + r2] = f2bf(acc[r]);
                }
            }
        }
        __syncthreads();

        // ---- G3 MFMA: wave w does row-tiles mt3 = 2w, 2w+1 (rows = (n1=mt3, n2)) ----
        #pragma unroll
        for (int t = 0; t < 2; ++t) {
            bf16x8 a3 = *(const bf16x8*)&sT2[((w * 2 + t) * 16 + col) * 40 + q * 8];
            acc3[t] = __builtin_amdgcn_mfma_f32_16x16x32_bf16(a3, b3[s].v, acc3[t], 0, 0, 0);
        }
    }

    // ---- epilogue: y = acc3 + bias; D row = n2, col = n3, tile = n1 ----
    float* outb = out + (size_t)b * 4096;
    #pragma unroll
    for (int t = 0; t < 2; ++t) {
        #pragma unroll
        for (int r = 0; r < 4; ++r) {
            const int idx = ((w * 2 + t) * 16 + q * 4 + r) * 16 + col;
            outb[idx] = acc3[t][r] + bias[idx];
        }
    }
}

extern "C" void kernel_launch(void* const* d_in, const int* in_sizes, int n_in,
                              void* d_out, int out_size, void* d_ws, size_t ws_size,
                              hipStream_t stream) {
    const float* x    = (const float*)d_in[0];
    const float* c0   = (const float*)d_in[1];  // (1,16,16,8)
    const float* c1   = (const float*)d_in[2];  // (8,16,16,8)
    const float* c2   = (const float*)d_in[3];  // (8,16,16,1)
    const float* bias = (const float*)d_in[4];  // (4096,)
    float* out = (float*)d_out;

    tt_mfma_kernel<<<4096, 512, 0, stream>>>(x, c0, c1, c2, bias, out);
}

// Round 3
// 235.548 us; speedup vs baseline: 8.2612x; 1.4945x over previous
//
#include <hip/hip_runtime.h>

// TT-linear, all three stages as bf16 MFMA (16x16x32, verified layouts only).
// One 512-thread WG (8 waves) per token; slab loop over m3 groups of 4.
//   G1: T1[(m2,m3l),(n1,r1)] = X^T @ C0   (K=16, zero-padded to 32; A from
//       GLOBAL x directly, B=C0 in registers -> zero LDS reads in G1)
//   G2: T2[(m3l,n1),(n2,r2)] = T1 @ C1    (K=128; A from sA2, B=C1 in regs)
//   G3: Y[(n1,n2),n3]       += T2 @ C2    (K=32/slab, acc in regs across slabs)
// Wave w owns m-tiles {2(w&1),2(w&1)+1} x n-tiles {2(w>>1),2(w>>1)+1} in G1/G2
// (keeps C1 frags at 32 VGPR so __launch_bounds__(512,4) holds 2 WG/CU).
// 2 barriers per slab (G1->G2 over sA2, G2->G3 over sT2); no other hazards.

typedef __attribute__((ext_vector_type(8))) short bf16x8;
typedef __attribute__((ext_vector_type(4))) float f32x4;

__device__ __forceinline__ unsigned short f2bf(float f) {
    unsigned u = __builtin_bit_cast(unsigned, f);
    u += 0x7FFFu + ((u >> 16) & 1u);   // round-to-nearest-even
    return (unsigned short)(u >> 16);
}

union BF8 { bf16x8 v; unsigned short s[8]; uint4 u4; };

#define SA 136   // sA2 row stride (elems): 272B -> row-start dword = 4c mod 32, uniform with +4q
#define ST 40    // sT2 row stride (elems): start dword 20c+4q -> (5c+q)%8 uniform

__global__ __launch_bounds__(512, 4) void tt_mfma2_kernel(
    const float* __restrict__ x, const float* __restrict__ c0,
    const float* __restrict__ c1, const float* __restrict__ c2,
    const float* __restrict__ bias, float* __restrict__ out)
{
    __shared__ unsigned short sA2[64 * SA];    // T1: row m3l*16+n1, col m2*8+r1 (17.4 KB)
    __shared__ unsigned short sT2[256 * ST];   // T2: row n1*16+n2, col m3l*8+r2 (20.5 KB)

    const int b    = blockIdx.x;
    const int tid  = threadIdx.x;
    const int w    = tid >> 6;
    const int lane = tid & 63;
    const int q    = lane >> 4;
    const int c    = lane & 15;
    const int mtp  = (w & 1) * 2;    // G1/G2 m-tiles {mtp, mtp+1}
    const int ntp  = (w >> 1) * 2;   // G1/G2 n-tiles {ntp, ntp+1}

    const float* xb = x + (size_t)b * 4096;

    // ---- G1 B-frags (C0), registers, K=16 zero-padded: q>=2 rows are zero ----
    BF8 bc0[2];
    #pragma unroll
    for (int i = 0; i < 2; ++i) {
        const int n1 = (ntp + i) * 2 + (c >> 3), r1 = c & 7;
        #pragma unroll
        for (int j = 0; j < 8; ++j)
            bc0[i].s[j] = (q < 2) ? f2bf(c0[(q * 8 + j) * 128 + n1 * 8 + r1]) : (unsigned short)0;
    }
    // ---- G2 B-frags (C1), registers: k = k4*32 + q*8 + j -> (m2=k4*4+q, r1=j) ----
    BF8 bF[2][4];
    #pragma unroll
    for (int i = 0; i < 2; ++i) {
        const int n2 = (ntp + i) * 2 + (c >> 3), r2 = c & 7;
        #pragma unroll
        for (int k4 = 0; k4 < 4; ++k4) {
            const int m2 = k4 * 4 + q;
            #pragma unroll
            for (int j = 0; j < 8; ++j)
                bF[i][k4].s[j] = f2bf(c1[((j * 16 + m2) * 16 + n2) * 8 + r2]);
        }
    }
    // ---- G3 B-frags (C2): k = q*8+j -> (m3l=q, r2=j); per slab s: m3 = s*4+q ----
    BF8 b3[4];
    #pragma unroll
    for (int s = 0; s < 4; ++s)
        #pragma unroll
        for (int j = 0; j < 8; ++j)
            b3[s].s[j] = f2bf(c2[(j * 16 + s * 4 + q) * 16 + c]);

    f32x4 acc3[2] = {{0.f,0.f,0.f,0.f},{0.f,0.f,0.f,0.f}};
    const f32x4 zero = {0.f,0.f,0.f,0.f};

    for (int s = 0; s < 4; ++s) {
        // ---- G1: A-frags straight from global x; MFMA; scatter D -> sA2 ----
        #pragma unroll
        for (int t = 0; t < 2; ++t) {
            const int mt = mtp + t;
            BF8 a1;
            if (q < 2) {
                const int m2 = mt * 4 + (c >> 2);
                const int m3 = s * 4 + (c & 3);
                #pragma unroll
                for (int j = 0; j < 8; ++j)
                    a1.s[j] = f2bf(xb[(q * 8 + j) * 256 + m2 * 16 + m3]);
            } else {
                a1.s[0]=0;a1.s[1]=0;a1.s[2]=0;a1.s[3]=0;a1.s[4]=0;a1.s[5]=0;a1.s[6]=0;a1.s[7]=0;
            }
            #pragma unroll
            for (int i = 0; i < 2; ++i) {
                f32x4 acc = __builtin_amdgcn_mfma_f32_16x16x32_bf16(a1.v, bc0[i].v, zero, 0, 0, 0);
                // D: row q*4+r -> (m2 = mt*4+q, m3l = r); col c -> (n1, r1)
                const int n1 = (ntp + i) * 2 + (c >> 3), r1 = c & 7;
                #pragma unroll
                for (int r = 0; r < 4; ++r)
                    sA2[(r * 16 + n1) * SA + (mt * 4 + q) * 8 + r1] = f2bf(acc[r]);
            }
        }
        __syncthreads();

        // ---- G2: A from sA2 (b128, conflict-free), MFMA, scatter -> sT2 ----
        #pragma unroll
        for (int t = 0; t < 2; ++t) {
            const int mt2 = mtp + t;      // = m3l
            bf16x8 aF[4];
            #pragma unroll
            for (int k4 = 0; k4 < 4; ++k4)
                aF[k4] = *(const bf16x8*)&sA2[(mt2 * 16 + c) * SA + k4 * 32 + q * 8];
            #pragma unroll
            for (int i = 0; i < 2; ++i) {
                f32x4 acc = zero;
                #pragma unroll
                for (int k4 = 0; k4 < 4; ++k4)
                    acc = __builtin_amdgcn_mfma_f32_16x16x32_bf16(aF[k4], bF[i][k4].v, acc, 0, 0, 0);
                const int n2 = (ntp + i) * 2 + (c >> 3), r2 = c & 7;
                #pragma unroll
                for (int r = 0; r < 4; ++r)       // D row q*4+r = n1
                    sT2[((q * 4 + r) * 16 + n2) * ST + mt2 * 8 + r2] = f2bf(acc[r]);
            }
        }
        __syncthreads();

        // ---- G3: A from sT2, accumulate Y in registers across slabs ----
        #pragma unroll
        for (int t = 0; t < 2; ++t) {
            const int t3 = w * 2 + t;     // = n1 tile
            bf16x8 a3 = *(const bf16x8*)&sT2[(t3 * 16 + c) * ST + q * 8];
            acc3[t] = __builtin_amdgcn_mfma_f32_16x16x32_bf16(a3, b3[s].v, acc3[t], 0, 0, 0);
        }
        // next-slab G1 writes sA2; G2(s) finished reading it before bar2 -> safe
    }

    // ---- epilogue: Y row = n1*16+n2 (n1 = t3, n2 = q*4+r), col = n3 = c ----
    float* outb = out + (size_t)b * 4096;
    #pragma unroll
    for (int t = 0; t < 2; ++t) {
        #pragma unroll
        for (int r = 0; r < 4; ++r) {
            const int idx = ((w * 2 + t) * 16 + q * 4 + r) * 16 + c;
            outb[idx] = acc3[t][r] + bias[idx];
        }
    }
}

extern "C" void kernel_launch(void* const* d_in, const int* in_sizes, int n_in,
                              void* d_out, int out_size, void* d_ws, size_t ws_size,
                              hipStream_t stream) {
    const float* x    = (const float*)d_in[0];
    const float* c0   = (const float*)d_in[1];  // (1,16,16,8)
    const float* c1   = (const float*)d_in[2];  // (8,16,16,8)
    const float* c2   = (const float*)d_in[3];  // (8,16,16,1)
    const float* bias = (const float*)d_in[4];  // (4096,)
    float* out = (float*)d_out;

    tt_mfma2_kernel<<<4096, 512, 0, stream>>>(x, c0, c1, c2, bias, out);
}

// Round 4
// 187.442 us; speedup vs baseline: 10.3814x; 1.2566x over previous
//
#include <hip/hip_runtime.h>

// TT-linear, 3 chained bf16 MFMA stages, 512-thread WG, 4 TOKENS per WG
// (grid 1024) so the C0/C1/C2 register-fragment prologue is amortized 4x.
//   G1: T1[(m2),(n1,r1)] per m3-slab = X^T @ C0 (K=16 zero-padded; A from global)
//   G2: T2[(n2,n1),(m3l,r2)] = T1 @ C1          (K=128; A from sA2, B in regs)
//   G3: Y[(n1,n2),n3] += T2 @ C2                (K=32/slab, acc in regs)
// LDS bank math (verified by hand, dword-bank = (byte/4)%32):
//   sA2 stride SA=160: G1 scatter bank = 16*c3 + 4*q + pair -> all 32 banks x2
//     (conflict-free); G2 b128 reads start {16c+4q} -> 8 starts x 4 dw uniform.
//   sT2 row map p = n2*16+n1, ST=36: G2 scatter bank = 8q + pair (+2-way c3,
//     free per m136); G3 reads as 2xb64 (8B-aligned only), starts uniform.
// f32->bf16 via v_cvt_pk_bf16_f32 when available (1 inst / 2 elems).

typedef __attribute__((ext_vector_type(8))) short bf16x8;
typedef __attribute__((ext_vector_type(4))) float f32x4;

__device__ __forceinline__ unsigned short f2bf(float f) {
    unsigned u = __builtin_bit_cast(unsigned, f);
    u += 0x7FFFu + ((u >> 16) & 1u);   // RNE
    return (unsigned short)(u >> 16);
}

__device__ __forceinline__ unsigned f2bf_pk(float lo, float hi) {
#if __has_builtin(__builtin_amdgcn_cvt_pk_bf16_f32)
    typedef __attribute__((ext_vector_type(2))) __bf16 bf2;
    bf2 r = __builtin_amdgcn_cvt_pk_bf16_f32(lo, hi);
    return __builtin_bit_cast(unsigned, r);
#else
    return (unsigned)f2bf(lo) | ((unsigned)f2bf(hi) << 16);
#endif
}

union BF8 { bf16x8 v; unsigned short s[8]; unsigned u[4]; uint4 u4; };

#define SA 160   // sA2 row stride (elems)
#define ST 36    // sT2 row stride (elems); rows only 8B-aligned -> b64 reads

__global__ __launch_bounds__(512, 4) void tt_mfma3_kernel(
    const float* __restrict__ x, const float* __restrict__ c0,
    const float* __restrict__ c1, const float* __restrict__ c2,
    const float* __restrict__ bias, float* __restrict__ out)
{
    __shared__ unsigned short sA2[64 * SA];    // T1: row m3l*16+n1, col m2*8+r1 (20 KB)
    __shared__ unsigned short sT2[256 * ST];   // T2: row n2*16+n1,  col m3l*8+r2 (18 KB)

    const int tid  = threadIdx.x;
    const int w    = tid >> 6;
    const int lane = tid & 63;
    const int q    = lane >> 4;
    const int c    = lane & 15;
    const int mtp  = (w & 1) * 2;    // G1/G2 m-tiles {mtp, mtp+1}
    const int ntp  = (w >> 1) * 2;   // G1/G2 n-tiles {ntp, ntp+1}

    // ---- fragment prologue (ONCE per WG, serves 4 tokens) ----
    BF8 bc0[2];                       // G1 B (C0), K=16 zero-padded: q>=2 rows zero
    #pragma unroll
    for (int i = 0; i < 2; ++i) {
        const int n1 = (ntp + i) * 2 + (c >> 3), r1 = c & 7;
        if (q < 2) {
            const float* p = &c0[(q * 8) * 128 + n1 * 8 + r1];
            #pragma unroll
            for (int u = 0; u < 4; ++u)
                bc0[i].u[u] = f2bf_pk(p[(2 * u) * 128], p[(2 * u + 1) * 128]);
        } else {
            bc0[i].u[0] = bc0[i].u[1] = bc0[i].u[2] = bc0[i].u[3] = 0;
        }
    }
    BF8 bF[2][4];                     // G2 B (C1): k = k4*32+q*8+j -> (m2=k4*4+q, r1=j)
    #pragma unroll
    for (int i = 0; i < 2; ++i) {
        const int n2 = (ntp + i) * 2 + (c >> 3), r2 = c & 7;
        #pragma unroll
        for (int k4 = 0; k4 < 4; ++k4) {
            const int m2 = k4 * 4 + q;
            const float* p = &c1[(m2 * 16 + n2) * 8 + r2];   // + j*2048
            #pragma unroll
            for (int u = 0; u < 4; ++u)
                bF[i][k4].u[u] = f2bf_pk(p[(2 * u) * 2048], p[(2 * u + 1) * 2048]);
        }
    }
    BF8 b3[4];                        // G3 B (C2): k = q*8+j -> (m3l=q, r2=j)
    #pragma unroll
    for (int s = 0; s < 4; ++s) {
        const float* p = &c2[(s * 4 + q) * 16 + c];          // + j*256
        #pragma unroll
        for (int u = 0; u < 4; ++u)
            b3[s].u[u] = f2bf_pk(p[(2 * u) * 256], p[(2 * u + 1) * 256]);
    }

    const f32x4 zero = {0.f, 0.f, 0.f, 0.f};

    for (int tok = 0; tok < 4; ++tok) {
        const int b = blockIdx.x * 4 + tok;
        const float* xb = x + (size_t)b * 4096;

        f32x4 acc3[2] = {{0.f,0.f,0.f,0.f},{0.f,0.f,0.f,0.f}};

        for (int s = 0; s < 4; ++s) {
            // ---- G1: A from global x; D scatter -> sA2 (conflict-free) ----
            #pragma unroll
            for (int t = 0; t < 2; ++t) {
                const int mt = mtp + t;
                BF8 a1;
                if (q < 2) {
                    const int m2 = mt * 4 + (c >> 2);
                    const int m3 = s * 4 + (c & 3);
                    const float* xp = xb + (q * 8) * 256 + m2 * 16 + m3;
                    #pragma unroll
                    for (int u = 0; u < 4; ++u)
                        a1.u[u] = f2bf_pk(xp[(2 * u) * 256], xp[(2 * u + 1) * 256]);
                } else {
                    a1.u[0] = a1.u[1] = a1.u[2] = a1.u[3] = 0;
                }
                #pragma unroll
                for (int i = 0; i < 2; ++i) {
                    f32x4 acc = __builtin_amdgcn_mfma_f32_16x16x32_bf16(a1.v, bc0[i].v, zero, 0, 0, 0);
                    // D: (m2 = mt*4+q, m3l = r); (n1, r1) from c
                    const int n1 = (ntp + i) * 2 + (c >> 3), r1 = c & 7;
                    const unsigned p01 = f2bf_pk(acc[0], acc[1]);
                    const unsigned p23 = f2bf_pk(acc[2], acc[3]);
                    unsigned short* bp = &sA2[n1 * SA + (mt * 4 + q) * 8 + r1];
                    bp[0 * 16 * SA] = (unsigned short)p01;
                    bp[1 * 16 * SA] = (unsigned short)(p01 >> 16);
                    bp[2 * 16 * SA] = (unsigned short)p23;
                    bp[3 * 16 * SA] = (unsigned short)(p23 >> 16);
                }
            }
            __syncthreads();

            // ---- G2: A from sA2 (b128, uniform), D scatter -> sT2 ----
            #pragma unroll
            for (int t = 0; t < 2; ++t) {
                const int mt2 = mtp + t;      // = m3l
                bf16x8 aF[4];
                #pragma unroll
                for (int k4 = 0; k4 < 4; ++k4)
                    aF[k4] = *(const bf16x8*)&sA2[(mt2 * 16 + c) * SA + k4 * 32 + q * 8];
                #pragma unroll
                for (int i = 0; i < 2; ++i) {
                    f32x4 acc = zero;
                    #pragma unroll
                    for (int k4 = 0; k4 < 4; ++k4)
                        acc = __builtin_amdgcn_mfma_f32_16x16x32_bf16(aF[k4], bF[i][k4].v, acc, 0, 0, 0);
                    // D rows = n1 = q*4+r; cols (n2, r2); row map p = n2*16+n1
                    const int n2 = (ntp + i) * 2 + (c >> 3), r2 = c & 7;
                    const unsigned p01 = f2bf_pk(acc[0], acc[1]);
                    const unsigned p23 = f2bf_pk(acc[2], acc[3]);
                    unsigned short* bp = &sT2[(n2 * 16 + q * 4) * ST + mt2 * 8 + r2];
                    bp[0 * ST] = (unsigned short)p01;
                    bp[1 * ST] = (unsigned short)(p01 >> 16);
                    bp[2 * ST] = (unsigned short)p23;
                    bp[3 * ST] = (unsigned short)(p23 >> 16);
                }
            }
            __syncthreads();

            // ---- G3: A row p = t3*16+c -> (n2 = t3, n1 = c); k = m3l*8+r2 ----
            #pragma unroll
            for (int t = 0; t < 2; ++t) {
                const int t3 = w * 2 + t;     // = n2 tile
                union { bf16x8 v; uint2 d[2]; } a3;
                const unsigned short* ap = &sT2[(t3 * 16 + c) * ST + q * 8];
                a3.d[0] = *(const uint2*)ap;
                a3.d[1] = *(const uint2*)(ap + 4);
                acc3[t] = __builtin_amdgcn_mfma_f32_16x16x32_bf16(a3.v, b3[s].v, acc3[t], 0, 0, 0);
            }
            // next G1 writes sA2 only after the s+1 (or next-token) first barrier
        }

        // ---- epilogue: element (n1 = q*4+r, n2 = t3, n3 = c) ----
        float* outb = out + (size_t)b * 4096;
        #pragma unroll
        for (int t = 0; t < 2; ++t) {
            #pragma unroll
            for (int r = 0; r < 4; ++r) {
                const int idx = (q * 4 + r) * 256 + (w * 2 + t) * 16 + c;
                outb[idx] = acc3[t][r] + bias[idx];
            }
        }
    }
}

extern "C" void kernel_launch(void* const* d_in, const int* in_sizes, int n_in,
                              void* d_out, int out_size, void* d_ws, size_t ws_size,
                              hipStream_t stream) {
    const float* x    = (const float*)d_in[0];
    const float* c0   = (const float*)d_in[1];  // (1,16,16,8)
    const float* c1   = (const float*)d_in[2];  // (8,16,16,8)
    const float* c2   = (const float*)d_in[3];  // (8,16,16,1)
    const float* bias = (const float*)d_in[4];  // (4096,)
    float* out = (float*)d_out;

    tt_mfma3_kernel<<<1024, 512, 0, stream>>>(x, c0, c1, c2, bias, out);
}